// Round 4
// baseline (92.270 us; speedup 1.0000x reference)
//
#include <hip/hip_runtime.h>

// LIF recurrence: mem = 0.9*mem + x; spike = (mem >= 1); record; mem -= spike.
// T=20, elementwise-independent. Output: [spikes T*N][mems T*N], fp32.
//
// R4: write-stream minimization. Previous rounds wrote all 40 output planes
// concurrently (~40 interleaved streams per HBM channel -> row thrash,
// ~2.4 TB/s vs the 6.1 TB/s the harness's own fill achieves). Now: work-items
// ordered (type, t-group) outer / chunk inner; a persistent 512-block grid
// grid-strides through them in output-address order, so at any instant only
// ~5 plane-streams are active, each swept sequentially. Each thread recomputes
// the recurrence up to its group (<=20 steps, bit-exact; ~5x recompute is
// ~3.5us VALU total -- negligible vs the 14us write roofline).
//
// Numerics: forced mul-then-add (__fmul_rn/__fadd_rn), no FMA contraction --
// 1-ulp drift flips the >=1.0 threshold (absmax=1.0 failure mode).

#define TSTEPS 20
#define TPER 5                 // planes per group
#define NGROUPS (TSTEPS / TPER)  // 4
#define N4 131072              // float4 per plane (64*8192/4)
#define CHUNKS 512             // 4 KB chunks per plane (N4/256)

typedef float v4f __attribute__((ext_vector_type(4)));

template <int TLO, bool SPIKES>
__device__ __forceinline__ void run_store(const v4f xv, v4f* __restrict__ dst,
                                          int n4) {
    float m0 = 0.f, m1 = 0.f, m2 = 0.f, m3 = 0.f;
#pragma unroll
    for (int t = 0; t < TLO + TPER; ++t) {
        m0 = __fadd_rn(__fmul_rn(0.9f, m0), xv.x);
        m1 = __fadd_rn(__fmul_rn(0.9f, m1), xv.y);
        m2 = __fadd_rn(__fmul_rn(0.9f, m2), xv.z);
        m3 = __fadd_rn(__fmul_rn(0.9f, m3), xv.w);

        float s0 = (m0 >= 1.0f) ? 1.0f : 0.0f;
        float s1 = (m1 >= 1.0f) ? 1.0f : 0.0f;
        float s2 = (m2 >= 1.0f) ? 1.0f : 0.0f;
        float s3 = (m3 >= 1.0f) ? 1.0f : 0.0f;

        if (t >= TLO) {
            v4f v;
            if (SPIKES) { v.x = s0; v.y = s1; v.z = s2; v.w = s3; }
            else        { v.x = m0; v.y = m1; v.z = m2; v.w = m3; }
            __builtin_nontemporal_store(v, dst + (size_t)(t - TLO) * n4);
        }

        m0 -= s0;
        m1 -= s1;
        m2 -= s2;
        m3 -= s3;
    }
}

__global__ __launch_bounds__(256) void
TemporalEncoding_57672820850797_kernel(const v4f* __restrict__ x,
                                       float* __restrict__ out, int n4) {
    v4f* out4 = reinterpret_cast<v4f*>(out);
    const int total = 2 * NGROUPS * CHUNKS;  // 4096 work-items, address order

    for (int w = blockIdx.x; w < total; w += gridDim.x) {
        const int type  = w >> 11;          // 0 = spikes, 1 = mems
        const int r     = w & 2047;
        const int g     = r >> 9;           // t-group 0..3
        const int chunk = r & (CHUNKS - 1); // 4 KB chunk within plane
        const int i     = chunk * 256 + threadIdx.x;  // float4 index in plane

        const v4f xv = x[i];  // 2 MB hot input, L2/L3-resident

        v4f* dst = out4 + (size_t)(type * TSTEPS + g * TPER) * n4 + i;
        switch ((type << 2) | g) {
            case 0: run_store< 0, true >(xv, dst, n4); break;
            case 1: run_store< 5, true >(xv, dst, n4); break;
            case 2: run_store<10, true >(xv, dst, n4); break;
            case 3: run_store<15, true >(xv, dst, n4); break;
            case 4: run_store< 0, false>(xv, dst, n4); break;
            case 5: run_store< 5, false>(xv, dst, n4); break;
            case 6: run_store<10, false>(xv, dst, n4); break;
            case 7: run_store<15, false>(xv, dst, n4); break;
        }
    }
}

extern "C" void kernel_launch(void* const* d_in, const int* in_sizes, int n_in,
                              void* d_out, int out_size, void* d_ws, size_t ws_size,
                              hipStream_t stream) {
    const float* x = (const float*)d_in[0];
    float* out = (float*)d_out;
    const int n4 = in_sizes[0] / 4;  // 131072
    const int block = 256;
    const int grid = 512;            // persistent: 2 blocks/CU, tight sweep window
    TemporalEncoding_57672820850797_kernel<<<grid, block, 0, stream>>>(
        (const v4f*)x, out, n4);
}